// Round 3
// baseline (418.574 us; speedup 1.0000x reference)
//
#include <hip/hip_runtime.h>

// Problem constants (from reference): T=100 time steps, B=256, F=4096.
// Output: [B, T, F] float32 = 419.4 MB, write-only. Write-bandwidth-bound.
//
// History:
//  r0/r2 (verified, ~408 us): thread-per-(b,f4) walking t. Kernel portion
//    ~138 us = 3.0 TB/s writes. NT vs plain store A/B (r2): NO difference ->
//    cache policy exonerated.
//  r1 (FAILED post-timing check): global sliding-window with x re-read
//    throughout kernel lifetime. Lesson: inputs must be read ONCE at kernel
//    start; keep per-thread reads up front, before the long store phase.
//
// r3 single-variable change vs r2: write ORDERING. Same store count, same
// coalescing, same bytes -- but each block now owns a CONTIGUOUS 400 KB slab
// out[b, t0:t0+25, :] and streams it strictly sequentially (16 KB per t-row),
// instead of 4 KB chunks at 16 KB stride with the whole grid scattered over
// the full 419 MB surface. Theory: DRAM page locality is what separates our
// 3.0 TB/s from the fill kernel's 6.2 TB/s on this same buffer.
constexpr int T  = 100;
constexpr int B  = 256;
constexpr int F  = 4096;
constexpr int F4 = F / 4;               // float4 slots per (b,t) row = 1024

typedef float floatx4 __attribute__((ext_vector_type(4)));

constexpr int BLOCK     = 256;
constexpr int TCHUNK    = 25;           // t-rows per block (100/4)
constexpr int BLK_PER_B = T / TCHUNK;   // 4 blocks per batch row
constexpr int NBLK      = B * BLK_PER_B;// 1024 blocks -> 4 blocks/CU

__global__ __launch_bounds__(BLOCK) void spike_kernel(
    const float* __restrict__ x,
    const float* __restrict__ delays,
    float* __restrict__ out)
{
    const int tid = threadIdx.x;
    const int b   = blockIdx.x >> 2;            // batch row
    const int t0  = (blockIdx.x & 3) * TCHUNK;  // this block's t window

    // Match numpy float32 semantics exactly: separate mul / sub / mul with
    // round-to-nearest, NO fma contraction (hipcc default -ffp-contract=fast
    // would shift st by 1 near integer boundaries). Then trunc-toward-zero
    // cast (.astype(int32)) and clip to [0, T-1].
    auto spike_time = [](float xi, float di) -> int {
        float p  = __fmul_rn(xi, di);
        float s  = __fsub_rn(1.0f, p);
        float v  = __fmul_rn(s, 99.0f);   // (T-1) = 99
        int   st = (int)v;                // trunc toward zero
        st = st < 0 ? 0 : st;
        st = st > (T - 1) ? (T - 1) : st;
        return st;
    };

    // ---- Input phase: ALL reads complete here, at kernel start (r1 lesson).
    // Block covers the full F axis: thread handles f4 slots {tid + 256*j}.
    // 16 spike times live in registers for the whole store phase; all
    // indices below are compile-time after unroll (no scratch spill).
    int st[4][4];
#pragma unroll
    for (int j = 0; j < 4; ++j) {
        const int f4s = (j << 8) + tid;
        const floatx4 xv = reinterpret_cast<const floatx4*>(x)[(b << 10) + f4s];
        const floatx4 dv = reinterpret_cast<const floatx4*>(delays)[f4s];
        st[j][0] = spike_time(xv.x, dv.x);
        st[j][1] = spike_time(xv.y, dv.y);
        st[j][2] = spike_time(xv.z, dv.z);
        st[j][3] = spike_time(xv.w, dv.w);
    }

    // ---- Store phase: block streams out[b, t0:t0+25, :] -- 400 KB fully
    // contiguous, advancing 16 KB per t-row. Lane i writes float4 slot
    // tid + 256*j of each row: consecutive lanes -> consecutive 16 B
    // (global_store_dwordx4, fully coalesced), rows written front to back.
    floatx4* outp = reinterpret_cast<floatx4*>(out)
                  + (((size_t)(b * T + t0)) << 10) + tid;

    for (int t = t0; t < t0 + TCHUNK; ++t, outp += F4) {
#pragma unroll
        for (int j = 0; j < 4; ++j) {
            floatx4 v;
            v.x = (t == st[j][0]) ? 1.0f : 0.0f;
            v.y = (t == st[j][1]) ? 1.0f : 0.0f;
            v.z = (t == st[j][2]) ? 1.0f : 0.0f;
            v.w = (t == st[j][3]) ? 1.0f : 0.0f;
            outp[j << 8] = v;   // plain store (r2: NT vs plain is neutral)
        }
    }
}

extern "C" void kernel_launch(void* const* d_in, const int* in_sizes, int n_in,
                              void* d_out, int out_size, void* d_ws, size_t ws_size,
                              hipStream_t stream)
{
    const float* x      = reinterpret_cast<const float*>(d_in[0]);   // [B, F]
    const float* delays = reinterpret_cast<const float*>(d_in[1]);   // [F]
    float* out          = reinterpret_cast<float*>(d_out);           // [B, T, F]

    spike_kernel<<<NBLK, BLOCK, 0, stream>>>(x, delays, out);
}

// Round 4
// 403.466 us; speedup vs baseline: 1.0374x; 1.0374x over previous
//
#include <hip/hip_runtime.h>

// Problem constants (from reference): T=100 time steps, B=256, F=4096.
// Output: [B, T, F] float32 = 419.4 MB, write-only. Write-bandwidth-bound.
//
// History:
//  r0/r2 (verified, ~408 us): thread-per-(b,f4) walking t; NT vs plain A/B
//    (r2) = neutral -> cache policy exonerated.
//  r1 (FAILED post-timing): sliding-window reading x throughout the kernel.
//    Lesson: read inputs ONCE, at the start of the launch.
//  r3 (418 us): block-contiguous 400 KB slabs = slightly WORSE -> write
//    ordering exonerated. Compute is ~4 us of VALU total -> not the bound
//    either. Dispatch-ID gaps between fills (35-190) show each timed replay
//    carries dozens of tiny restore dispatches -> suspect ~60+ us of fixed
//    graph-node overhead, i.e. the kernel may already be near the write
//    roofline (~70 us).
//
// r4 discriminating experiment: split into
//   K1: read x/delays at launch start (r1-safe), pack spike times into a
//       1 MB u8x4 table in workspace (~4 us).
//   K2: stream the 419 MB output in PURE output-linear order (identical
//       access pattern to the 6.2 TB/s fillBuffer), reading only the
//       L2-resident table. No input reads, minimal VALU per store.
// If dur_us doesn't drop, the kernel slice was never the bottleneck and we
// are at the harness floor.
constexpr int T  = 100;
constexpr int B  = 256;
constexpr int F  = 4096;
constexpr int F4 = F / 4;                 // float4 slots per (b,t) row = 1024

typedef float        floatx4 __attribute__((ext_vector_type(4)));
typedef unsigned int u32;

// ---------------- K1: spike-time table builder ----------------
// One thread per (b, f4): reads 16 B of x + 16 B of delays, writes one u32
// (4 packed u8 spike times, st < 100 fits u8) to ws[b*1024 + f4]. All input
// reads for the whole launch complete here, in the first ~4 us.
__global__ __launch_bounds__(256) void build_st(
    const float* __restrict__ x,
    const float* __restrict__ delays,
    u32* __restrict__ stw)
{
    const int idx = blockIdx.x * 256 + threadIdx.x;   // 0 .. B*F4-1
    const int f4  = idx & (F4 - 1);

    const floatx4 xv = reinterpret_cast<const floatx4*>(x)[idx];
    const floatx4 dv = reinterpret_cast<const floatx4*>(delays)[f4];

    // Match numpy float32 semantics exactly: separate mul / sub / mul with
    // round-to-nearest, NO fma contraction (hipcc default -ffp-contract=fast
    // would shift st by 1 near integer boundaries). Then trunc-toward-zero
    // cast (.astype(int32)) and clip to [0, T-1]. (Bit-identical to the
    // verified r0/r2 path.)
    auto sti = [](float xi, float di) -> u32 {
        float p  = __fmul_rn(xi, di);
        float s  = __fsub_rn(1.0f, p);
        float v  = __fmul_rn(s, 99.0f);   // (T-1) = 99
        int   st = (int)v;                // trunc toward zero
        st = st < 0 ? 0 : st;
        st = st > (T - 1) ? (T - 1) : st;
        return (u32)st;
    };

    const u32 w = sti(xv.x, dv.x)
                | (sti(xv.y, dv.y) << 8)
                | (sti(xv.z, dv.z) << 16)
                | (sti(xv.w, dv.w) << 24);
    stw[idx] = w;
}

// ---------------- K2: dense output-linear writer ----------------
constexpr int BLOCK  = 256;
constexpr int NBLK   = 2048;              // 8 blocks/CU, all resident
constexpr int G      = NBLK * BLOCK;      // 524288 float4 = 8 MB per sweep
constexpr int TOTAL4 = B * T * F4;        // 26,214,400 float4
constexpr int NITER  = TOTAL4 / G;        // 50, exact (no tail)
// G is a multiple of F4, so each thread's f4 is loop-invariant.

__global__ __launch_bounds__(BLOCK) void write_spikes(
    const u32* __restrict__ stw,
    float* __restrict__ out)
{
    const int tid0 = blockIdx.x * BLOCK + threadIdx.x;  // 0 .. G-1
    const int f4   = tid0 & (F4 - 1);                   // loop-invariant
    floatx4* out4  = reinterpret_cast<floatx4*>(out);

    int idx = tid0;                        // linear float4 index into out
    for (int k = 0; k < NITER; ++k, idx += G) {
        const int bt = idx >> 10;          // b*T + t, 0 .. 25599
        // exact /100 via u24 magic: valid for bt < 43690 (5243*100-2^19=12)
        const int b  = (bt * 5243) >> 19;
        const int t  = bt - b * 100;

        // 4 B/thread from the 1 MB table; wave reads 256 B contiguous,
        // fully L2-resident (re-read 100x while the window crosses b).
        const u32 w = stw[(b << 10) | f4];

        floatx4 v;
        v.x = (t == (int)( w        & 255u)) ? 1.0f : 0.0f;
        v.y = (t == (int)((w >> 8)  & 255u)) ? 1.0f : 0.0f;
        v.z = (t == (int)((w >> 16) & 255u)) ? 1.0f : 0.0f;
        v.w = (t == (int)( w >> 24        )) ? 1.0f : 0.0f;

        // Whole grid writes one dense 8 MB window sliding linearly over the
        // 419 MB output -- identical pattern to fillBuffer (6.2 TB/s).
        out4[idx] = v;
    }
}

// ---------------- fallback (verified r2 kernel) if ws too small ----------
__global__ __launch_bounds__(256) void spike_kernel_fb(
    const float* __restrict__ x,
    const float* __restrict__ delays,
    float* __restrict__ out)
{
    const int idx = blockIdx.x * blockDim.x + threadIdx.x;
    const int f4  = idx & (F4 - 1);
    const int b   = idx >> 10;

    const floatx4 xv = reinterpret_cast<const floatx4*>(x)[idx];
    const floatx4 dv = reinterpret_cast<const floatx4*>(delays)[f4];

    auto spike_time = [](float xi, float di) -> int {
        float p  = __fmul_rn(xi, di);
        float s  = __fsub_rn(1.0f, p);
        float v  = __fmul_rn(s, 99.0f);
        int   st = (int)v;
        st = st < 0 ? 0 : st;
        st = st > (T - 1) ? (T - 1) : st;
        return st;
    };
    const int st0 = spike_time(xv.x, dv.x);
    const int st1 = spike_time(xv.y, dv.y);
    const int st2 = spike_time(xv.z, dv.z);
    const int st3 = spike_time(xv.w, dv.w);

    floatx4* outp = reinterpret_cast<floatx4*>(out) + (size_t)b * T * F4 + f4;
#pragma unroll 4
    for (int t = 0; t < T; ++t) {
        floatx4 v;
        v.x = (t == st0) ? 1.0f : 0.0f;
        v.y = (t == st1) ? 1.0f : 0.0f;
        v.z = (t == st2) ? 1.0f : 0.0f;
        v.w = (t == st3) ? 1.0f : 0.0f;
        outp[(size_t)t * F4] = v;
    }
}

extern "C" void kernel_launch(void* const* d_in, const int* in_sizes, int n_in,
                              void* d_out, int out_size, void* d_ws, size_t ws_size,
                              hipStream_t stream)
{
    const float* x      = reinterpret_cast<const float*>(d_in[0]);   // [B, F]
    const float* delays = reinterpret_cast<const float*>(d_in[1]);   // [F]
    float* out          = reinterpret_cast<float*>(d_out);           // [B, T, F]

    const size_t needed = (size_t)B * F4 * sizeof(u32);              // 1 MB
    if (ws_size >= needed && d_ws != nullptr) {
        u32* stw = reinterpret_cast<u32*>(d_ws);
        build_st<<<B * F4 / 256, 256, 0, stream>>>(x, delays, stw);  // 1024 blk
        write_spikes<<<NBLK, BLOCK, 0, stream>>>(stw, out);
    } else {
        // workspace too small: verified r2 single-kernel path
        spike_kernel_fb<<<B * F4 / 256, 256, 0, stream>>>(x, delays, out);
    }
}